// Round 9
// baseline (20030.707 us; speedup 1.0000x reference)
//
#include <hip/hip_runtime.h>

#define NB 4096
#define ND 64
#define NH 256
#define NT 50
#define ROWS 16
#define THREADS 1024
#define GRID (NB / ROWS)   // 256 blocks = exactly 1 per CU, XCD-balanced

// Padded LDS layouts: 16-element groups at stride-20 floats (80 B) so the 4
// group-selecting lanes (q4) hit disjoint bank quads {0-3}{20-23}{8-11}{28-31}.
#define YIS 84            // yi row stride: (d>>4)*20 + (d&15)
#define ZS  324           // z row stride: (j>>4)*20 + (j&15)
#define RRS 68            // sRed row stride
#define RJS (ROWS * RRS)  // 1088: per-jhi block (16 rows)

__device__ __forceinline__ float fast_tanh(float x) {
  // tanh(x) = 1 - 2/(exp(2x)+1); safe at +-inf
  float e = __expf(2.0f * x);
  return 1.0f - 2.0f * __builtin_amdgcn_rcpf(e + 1.0f);
}

// quad-perm DPP butterfly add (VALU pipe, not LDS)
template <int CTRL>
__device__ __forceinline__ float dpp_add(float x) {
  int s = __builtin_amdgcn_update_dpp(0, __float_as_int(x), CTRL, 0xF, 0xF, true);
  return x + __int_as_float(s);
}
#define DPP_XOR1 0xB1  // quad_perm [1,0,3,2]
#define DPP_XOR2 0x4E  // quad_perm [2,3,0,1]

// 1024-thread workgroup: 16 waves MUST be co-resident -> 4 waves/EU by
// construction (r5/r8 showed attr-based routes stall at 2 waves/EU).
// Backend hard-caps VGPR at 128 for wgs=1024; r8's identical body compiled
// to 116 -> fits. waves_per_eu(2,4) is the proven-benign RA setting (r5).
extern "C" __global__
__attribute__((amdgpu_flat_work_group_size(THREADS, THREADS)))
__attribute__((amdgpu_waves_per_eu(2, 4)))
void ode_kernel(const float* __restrict__ y0,
                const float* __restrict__ tt,
                const float* __restrict__ W1,
                const float* __restrict__ b1,
                const float* __restrict__ W2,
                const float* __restrict__ b2,
                float* __restrict__ out)
{
  __shared__ float sYI[ROWS * YIS];   // 1344 floats
  __shared__ float sZ [ROWS * ZS];    // 5184 floats
  __shared__ float sRed[4 * RJS];     // 4352 floats  (43.5 KB total)

  const int tid  = threadIdx.x;
  const int wv   = tid >> 6;        // wave 0..15
  const int lane = tid & 63;
  const int d    = lane;            // state dim
  const int row  = (int)blockIdx.x * ROWS + wv;   // state row
  const int rh   = wv >> 2;         // row-quarter: both GEMMs work rows rh*4..+3
  const int q4   = lane & 3;        // G1 dgrp / G2 jlo (quad lane)
  const int jg   = (tid >> 2) & 63; // G1: j's 4jg..4jg+3 (4 waves/rh cover all)
  const int jhi  = wv & 3;          // G2: j-supergroup
  const int dg2  = lane >> 2;       // G2: d's 4dg2..4dg2+3

  // ---- weights in registers ----
  float w1_[16][4];   // [dd][jj] = W1[q4*16+dd][4jg+jj]
#pragma unroll
  for (int dd = 0; dd < 16; ++dd) {
    const float4 t = *(const float4*)&W1[(q4 * 16 + dd) * NH + 4 * jg];
    w1_[dd][0] = t.x; w1_[dd][1] = t.y; w1_[dd][2] = t.z; w1_[dd][3] = t.w;
  }
  const float4 b1v = *(const float4*)&b1[4 * jg];

  float w2_[16][4];   // [jj][dd] = W2[(jhi*4+q4)*16+jj][4dg2+dd]
#pragma unroll
  for (int jj = 0; jj < 16; ++jj) {
    const float4 t = *(const float4*)&W2[((jhi * 4 + q4) * 16 + jj) * ND + 4 * dg2];
    w2_[jj][0] = t.x; w2_[jj][1] = t.y; w2_[jj][2] = t.z; w2_[jj][3] = t.w;
  }
  const float b2d = b2[d];

  // state: y[row][d]
  float y = y0[row * ND + d];
  out[row * ND + d] = y;

  // precomputed LDS pointers
  const int yi_woff = wv * YIS + (d >> 4) * 20 + (d & 15);
  const float* yib = &sYI[(rh * 4) * YIS + q4 * 20];
  float*       zwb = &sZ[(rh * 4) * ZS + (jg >> 2) * 20 + 4 * (jg & 3)];
  const float* zrb = &sZ[(rh * 4) * ZS + (jhi * 4 + q4) * 20];
  float*       rwb = &sRed[jhi * RJS + (rh * 4) * RRS + 4 * dg2];
  const float* rob = &sRed[wv * RRS + d];

  // f(yi) = tanh(yi @ W1 + b1) @ W2 + b2, scalar slice per owner thread.
  auto feval = [&](float yiv) -> float {
    sYI[yi_woff] = yiv;
    __syncthreads();                     // Ba

    // ---- GEMM1: z[4 rows][4 j] partial over 16 dims (dgrp = q4) ----
    float z[4][4];
#pragma unroll
    for (int r = 0; r < 4; ++r)
#pragma unroll
      for (int jj = 0; jj < 4; ++jj) z[r][jj] = 0.0f;
#pragma unroll
    for (int r = 0; r < 4; ++r) {
#pragma unroll
      for (int q = 0; q < 4; ++q) {
        const float4 a = *(const float4*)(yib + r * YIS + 4 * q);
#pragma unroll
        for (int jj = 0; jj < 4; ++jj) {
          z[r][jj] = fmaf(a.x, w1_[4 * q + 0][jj], z[r][jj]);
          z[r][jj] = fmaf(a.y, w1_[4 * q + 1][jj], z[r][jj]);
          z[r][jj] = fmaf(a.z, w1_[4 * q + 2][jj], z[r][jj]);
          z[r][jj] = fmaf(a.w, w1_[4 * q + 3][jj], z[r][jj]);
        }
      }
    }
    // quad reduce over dgrp (deterministic butterfly, VALU pipe)
#pragma unroll
    for (int r = 0; r < 4; ++r)
#pragma unroll
      for (int jj = 0; jj < 4; ++jj)
        z[r][jj] = dpp_add<DPP_XOR2>(dpp_add<DPP_XOR1>(z[r][jj]));
    if (q4 == 0) {
#pragma unroll
      for (int r = 0; r < 4; ++r) {
        float4 zv;
        zv.x = fast_tanh(z[r][0] + b1v.x);
        zv.y = fast_tanh(z[r][1] + b1v.y);
        zv.z = fast_tanh(z[r][2] + b1v.z);
        zv.w = fast_tanh(z[r][3] + b1v.w);
        *(float4*)(zwb + r * ZS) = zv;
      }
    }
    __syncthreads();                     // Bb

    // ---- GEMM2: p[4 rows][4 d] partial over 16 j's (jgrp = jhi*4+q4) ----
    float p[4][4];
#pragma unroll
    for (int r = 0; r < 4; ++r)
#pragma unroll
      for (int dd = 0; dd < 4; ++dd) p[r][dd] = 0.0f;
#pragma unroll
    for (int r = 0; r < 4; ++r) {
#pragma unroll
      for (int q = 0; q < 4; ++q) {
        const float4 a = *(const float4*)(zrb + r * ZS + 4 * q);
#pragma unroll
        for (int dd = 0; dd < 4; ++dd) {
          p[r][dd] = fmaf(a.x, w2_[4 * q + 0][dd], p[r][dd]);
          p[r][dd] = fmaf(a.y, w2_[4 * q + 1][dd], p[r][dd]);
          p[r][dd] = fmaf(a.z, w2_[4 * q + 2][dd], p[r][dd]);
          p[r][dd] = fmaf(a.w, w2_[4 * q + 3][dd], p[r][dd]);
        }
      }
    }
#pragma unroll
    for (int r = 0; r < 4; ++r)
#pragma unroll
      for (int dd = 0; dd < 4; ++dd)
        p[r][dd] = dpp_add<DPP_XOR2>(dpp_add<DPP_XOR1>(p[r][dd]));
    if (q4 == 0) {
#pragma unroll
      for (int r = 0; r < 4; ++r)
        *(float4*)(rwb + r * RRS) = make_float4(p[r][0], p[r][1], p[r][2], p[r][3]);
    }
    __syncthreads();                     // Bc

    // owner (wv, d): combine 4 j-supergroups, fixed order
    float o = b2d;
#pragma unroll
    for (int jh = 0; jh < 4; ++jh) o += rob[jh * RJS];
    return o;
  };

  // Dormand-Prince 5(4) tableau (5th-order solution row)
  const float A10 = (float)(1.0 / 5.0);
  const float A20 = (float)(3.0 / 40.0),      A21 = (float)(9.0 / 40.0);
  const float A30 = (float)(44.0 / 45.0),     A31 = (float)(-56.0 / 15.0),
              A32 = (float)(32.0 / 9.0);
  const float A40 = (float)(19372.0 / 6561.0), A41 = (float)(-25360.0 / 2187.0),
              A42 = (float)(64448.0 / 6561.0), A43 = (float)(-212.0 / 729.0);
  const float A50 = (float)(9017.0 / 3168.0),  A51 = (float)(-355.0 / 33.0),
              A52 = (float)(46732.0 / 5247.0), A53 = (float)(49.0 / 176.0),
              A54 = (float)(-5103.0 / 18656.0);
  const float B0 = (float)(35.0 / 384.0),      B2 = (float)(500.0 / 1113.0),
              B3 = (float)(125.0 / 192.0),     B4 = (float)(-2187.0 / 6784.0),
              B5 = (float)(11.0 / 84.0);

  for (int ti = 0; ti < NT - 1; ++ti) {
    const float dt = (tt[ti + 1] - tt[ti]) * 0.25f;  // /SUBSTEPS, exact pow2
    for (int ss = 0; ss < 4; ++ss) {
      const float k0 = feval(y);

      float yi = fmaf(dt * A10, k0, y);
      const float k1 = feval(yi);

      yi = y;
      yi = fmaf(dt * A20, k0, yi); yi = fmaf(dt * A21, k1, yi);
      const float k2 = feval(yi);

      yi = y;
      yi = fmaf(dt * A30, k0, yi); yi = fmaf(dt * A31, k1, yi);
      yi = fmaf(dt * A32, k2, yi);
      const float k3 = feval(yi);

      yi = y;
      yi = fmaf(dt * A40, k0, yi); yi = fmaf(dt * A41, k1, yi);
      yi = fmaf(dt * A42, k2, yi); yi = fmaf(dt * A43, k3, yi);
      const float k4 = feval(yi);

      yi = y;
      yi = fmaf(dt * A50, k0, yi); yi = fmaf(dt * A51, k1, yi);
      yi = fmaf(dt * A52, k2, yi); yi = fmaf(dt * A53, k3, yi);
      yi = fmaf(dt * A54, k4, yi);
      const float k5 = feval(yi);

      // y_new = y + dt*(B0*k0 + B2*k2 + B3*k3 + B4*k4 + B5*k5)   (B1 = 0)
      y = fmaf(dt * B0, k0, y);
      y = fmaf(dt * B2, k2, y);
      y = fmaf(dt * B3, k3, y);
      y = fmaf(dt * B4, k4, y);
      y = fmaf(dt * B5, k5, y);
    }
    out[(size_t)(ti + 1) * NB * ND + row * ND + d] = y;
  }
}

extern "C" void kernel_launch(void* const* d_in, const int* in_sizes, int n_in,
                              void* d_out, int out_size, void* d_ws, size_t ws_size,
                              hipStream_t stream) {
  const float* y0 = (const float*)d_in[0];
  const float* tt = (const float*)d_in[1];
  const float* W1 = (const float*)d_in[2];
  const float* b1 = (const float*)d_in[3];
  const float* W2 = (const float*)d_in[4];
  const float* b2 = (const float*)d_in[5];
  float* out = (float*)d_out;

  hipLaunchKernelGGL(ode_kernel, dim3(GRID), dim3(THREADS), 0, stream,
                     y0, tt, W1, b1, W2, b2, out);
}

// Round 10
// 5708.812 us; speedup vs baseline: 3.5087x; 3.5087x over previous
//
#include <hip/hip_runtime.h>

#define NB 4096
#define ND 64
#define NH 256
#define NT 50
#define ROWS 8
#define THREADS 512
#define GRID (NB / ROWS)   // 512 blocks; 2 blocks/CU if 4 waves/EU schedulable

// Padded LDS layouts: 16-element groups at stride-20 floats (80 B) so the 4
// group-selecting lanes (q4) hit disjoint bank quads {0-3}{20-23}{8-11}{28-31}.
#define YIS 84            // yi row stride: (d>>4)*20 + (d&15)
#define ZS  324           // z row stride: (j>>4)*20 + (j&15)
#define RRS 68            // sRed row stride
#define RJS (8 * RRS)     // 544: per-jhi block

__device__ __forceinline__ float fast_tanh(float x) {
  // tanh(x) = 1 - 2/(exp(2x)+1); safe at +-inf
  float e = __expf(2.0f * x);
  return 1.0f - 2.0f * __builtin_amdgcn_rcpf(e + 1.0f);
}

// quad-perm DPP butterfly add (VALU pipe, not LDS)
template <int CTRL>
__device__ __forceinline__ float dpp_add(float x) {
  int s = __builtin_amdgcn_update_dpp(0, __float_as_int(x), CTRL, 0xF, 0xF, true);
  return x + __int_as_float(s);
}
#define DPP_XOR1 0xB1  // quad_perm [1,0,3,2]
#define DPP_XOR2 0x4E  // quad_perm [2,3,0,1]

// SINGLE-VARIABLE CHANGE vs r8 (5.71 ms): waves_per_eu (2,2) -> (2,4).
//   - min=2 keeps the RA budget that r5/r8 proved spill-free (~112-124 VGPR).
//   - max=4 removes the max=2 scheduler cap, letting the HW pack 2 blocks/CU
//     (= 4 waves/EU) if m69's occupancy rule (<=128 VGPR -> 4 waves/EU) holds.
// r9 lesson: wgs=1024 forces a 64-reg compile (71 GB scratch) -> never again.
extern "C" __global__
__attribute__((amdgpu_flat_work_group_size(THREADS, THREADS)))
__attribute__((amdgpu_waves_per_eu(2, 4)))
void ode_kernel(const float* __restrict__ y0,
                const float* __restrict__ tt,
                const float* __restrict__ W1,
                const float* __restrict__ b1,
                const float* __restrict__ W2,
                const float* __restrict__ b2,
                float* __restrict__ out)
{
  __shared__ float sYI[ROWS * YIS];   // 672 floats
  __shared__ float sZ [ROWS * ZS];    // 2592 floats
  __shared__ float sRed[4 * RJS];     // 2176 floats  (21.8 KB total)

  const int tid  = threadIdx.x;
  const int wv   = tid >> 6;        // wave 0..7
  const int lane = tid & 63;
  const int d    = lane;            // state dim
  const int row  = (int)blockIdx.x * ROWS + wv;   // state row
  const int rh   = wv >> 2;         // row-half: both GEMMs work rows rh*4..+3
  const int q4   = lane & 3;        // G1 dgrp / G2 jlo (quad lane)
  const int jg   = (tid >> 2) & 63; // G1: j's 4jg..4jg+3
  const int jhi  = wv & 3;          // G2: j-supergroup
  const int dg2  = lane >> 2;       // G2: d's 4dg2..4dg2+3

  // ---- weights in registers ----
  float w1_[16][4];   // [dd][jj] = W1[q4*16+dd][4jg+jj]
#pragma unroll
  for (int dd = 0; dd < 16; ++dd) {
    const float4 t = *(const float4*)&W1[(q4 * 16 + dd) * NH + 4 * jg];
    w1_[dd][0] = t.x; w1_[dd][1] = t.y; w1_[dd][2] = t.z; w1_[dd][3] = t.w;
  }
  const float4 b1v = *(const float4*)&b1[4 * jg];

  float w2_[16][4];   // [jj][dd] = W2[(jhi*4+q4)*16+jj][4dg2+dd]
#pragma unroll
  for (int jj = 0; jj < 16; ++jj) {
    const float4 t = *(const float4*)&W2[((jhi * 4 + q4) * 16 + jj) * ND + 4 * dg2];
    w2_[jj][0] = t.x; w2_[jj][1] = t.y; w2_[jj][2] = t.z; w2_[jj][3] = t.w;
  }
  const float b2d = b2[d];

  // state: y[row][d]
  float y = y0[row * ND + d];
  out[row * ND + d] = y;

  // precomputed LDS pointers
  const int yi_woff = wv * YIS + (d >> 4) * 20 + (d & 15);
  const float* yib = &sYI[(rh * 4) * YIS + q4 * 20];
  float*       zwb = &sZ[(rh * 4) * ZS + (jg >> 2) * 20 + 4 * (jg & 3)];
  const float* zrb = &sZ[(rh * 4) * ZS + (jhi * 4 + q4) * 20];
  float*       rwb = &sRed[jhi * RJS + (rh * 4) * RRS + 4 * dg2];
  const float* rob = &sRed[wv * RRS + d];

  // f(yi) = tanh(yi @ W1 + b1) @ W2 + b2, scalar slice per owner thread.
  auto feval = [&](float yiv) -> float {
    sYI[yi_woff] = yiv;
    __syncthreads();                     // Ba

    // ---- GEMM1: z[4 rows][4 j] partial over 16 dims (dgrp = q4) ----
    float z[4][4];
#pragma unroll
    for (int r = 0; r < 4; ++r)
#pragma unroll
      for (int jj = 0; jj < 4; ++jj) z[r][jj] = 0.0f;
#pragma unroll
    for (int r = 0; r < 4; ++r) {
#pragma unroll
      for (int q = 0; q < 4; ++q) {
        const float4 a = *(const float4*)(yib + r * YIS + 4 * q);
#pragma unroll
        for (int jj = 0; jj < 4; ++jj) {
          z[r][jj] = fmaf(a.x, w1_[4 * q + 0][jj], z[r][jj]);
          z[r][jj] = fmaf(a.y, w1_[4 * q + 1][jj], z[r][jj]);
          z[r][jj] = fmaf(a.z, w1_[4 * q + 2][jj], z[r][jj]);
          z[r][jj] = fmaf(a.w, w1_[4 * q + 3][jj], z[r][jj]);
        }
      }
    }
    // quad reduce over dgrp (deterministic butterfly, VALU pipe)
#pragma unroll
    for (int r = 0; r < 4; ++r)
#pragma unroll
      for (int jj = 0; jj < 4; ++jj)
        z[r][jj] = dpp_add<DPP_XOR2>(dpp_add<DPP_XOR1>(z[r][jj]));
    if (q4 == 0) {
#pragma unroll
      for (int r = 0; r < 4; ++r) {
        float4 zv;
        zv.x = fast_tanh(z[r][0] + b1v.x);
        zv.y = fast_tanh(z[r][1] + b1v.y);
        zv.z = fast_tanh(z[r][2] + b1v.z);
        zv.w = fast_tanh(z[r][3] + b1v.w);
        *(float4*)(zwb + r * ZS) = zv;
      }
    }
    __syncthreads();                     // Bb

    // ---- GEMM2: p[4 rows][4 d] partial over 16 j's (jgrp = jhi*4+q4) ----
    float p[4][4];
#pragma unroll
    for (int r = 0; r < 4; ++r)
#pragma unroll
      for (int dd = 0; dd < 4; ++dd) p[r][dd] = 0.0f;
#pragma unroll
    for (int r = 0; r < 4; ++r) {
#pragma unroll
      for (int q = 0; q < 4; ++q) {
        const float4 a = *(const float4*)(zrb + r * ZS + 4 * q);
#pragma unroll
        for (int dd = 0; dd < 4; ++dd) {
          p[r][dd] = fmaf(a.x, w2_[4 * q + 0][dd], p[r][dd]);
          p[r][dd] = fmaf(a.y, w2_[4 * q + 1][dd], p[r][dd]);
          p[r][dd] = fmaf(a.z, w2_[4 * q + 2][dd], p[r][dd]);
          p[r][dd] = fmaf(a.w, w2_[4 * q + 3][dd], p[r][dd]);
        }
      }
    }
#pragma unroll
    for (int r = 0; r < 4; ++r)
#pragma unroll
      for (int dd = 0; dd < 4; ++dd)
        p[r][dd] = dpp_add<DPP_XOR2>(dpp_add<DPP_XOR1>(p[r][dd]));
    if (q4 == 0) {
#pragma unroll
      for (int r = 0; r < 4; ++r)
        *(float4*)(rwb + r * RRS) = make_float4(p[r][0], p[r][1], p[r][2], p[r][3]);
    }
    __syncthreads();                     // Bc

    // owner (wv, d): combine 4 j-supergroups, fixed order
    float o = b2d;
#pragma unroll
    for (int jh = 0; jh < 4; ++jh) o += rob[jh * RJS];
    return o;
  };

  // Dormand-Prince 5(4) tableau (5th-order solution row)
  const float A10 = (float)(1.0 / 5.0);
  const float A20 = (float)(3.0 / 40.0),      A21 = (float)(9.0 / 40.0);
  const float A30 = (float)(44.0 / 45.0),     A31 = (float)(-56.0 / 15.0),
              A32 = (float)(32.0 / 9.0);
  const float A40 = (float)(19372.0 / 6561.0), A41 = (float)(-25360.0 / 2187.0),
              A42 = (float)(64448.0 / 6561.0), A43 = (float)(-212.0 / 729.0);
  const float A50 = (float)(9017.0 / 3168.0),  A51 = (float)(-355.0 / 33.0),
              A52 = (float)(46732.0 / 5247.0), A53 = (float)(49.0 / 176.0),
              A54 = (float)(-5103.0 / 18656.0);
  const float B0 = (float)(35.0 / 384.0),      B2 = (float)(500.0 / 1113.0),
              B3 = (float)(125.0 / 192.0),     B4 = (float)(-2187.0 / 6784.0),
              B5 = (float)(11.0 / 84.0);

  for (int ti = 0; ti < NT - 1; ++ti) {
    const float dt = (tt[ti + 1] - tt[ti]) * 0.25f;  // /SUBSTEPS, exact pow2
    for (int ss = 0; ss < 4; ++ss) {
      const float k0 = feval(y);

      float yi = fmaf(dt * A10, k0, y);
      const float k1 = feval(yi);

      yi = y;
      yi = fmaf(dt * A20, k0, yi); yi = fmaf(dt * A21, k1, yi);
      const float k2 = feval(yi);

      yi = y;
      yi = fmaf(dt * A30, k0, yi); yi = fmaf(dt * A31, k1, yi);
      yi = fmaf(dt * A32, k2, yi);
      const float k3 = feval(yi);

      yi = y;
      yi = fmaf(dt * A40, k0, yi); yi = fmaf(dt * A41, k1, yi);
      yi = fmaf(dt * A42, k2, yi); yi = fmaf(dt * A43, k3, yi);
      const float k4 = feval(yi);

      yi = y;
      yi = fmaf(dt * A50, k0, yi); yi = fmaf(dt * A51, k1, yi);
      yi = fmaf(dt * A52, k2, yi); yi = fmaf(dt * A53, k3, yi);
      yi = fmaf(dt * A54, k4, yi);
      const float k5 = feval(yi);

      // y_new = y + dt*(B0*k0 + B2*k2 + B3*k3 + B4*k4 + B5*k5)   (B1 = 0)
      y = fmaf(dt * B0, k0, y);
      y = fmaf(dt * B2, k2, y);
      y = fmaf(dt * B3, k3, y);
      y = fmaf(dt * B4, k4, y);
      y = fmaf(dt * B5, k5, y);
    }
    out[(size_t)(ti + 1) * NB * ND + row * ND + d] = y;
  }
}

extern "C" void kernel_launch(void* const* d_in, const int* in_sizes, int n_in,
                              void* d_out, int out_size, void* d_ws, size_t ws_size,
                              hipStream_t stream) {
  const float* y0 = (const float*)d_in[0];
  const float* tt = (const float*)d_in[1];
  const float* W1 = (const float*)d_in[2];
  const float* b1 = (const float*)d_in[3];
  const float* W2 = (const float*)d_in[4];
  const float* b2 = (const float*)d_in[5];
  float* out = (float*)d_out;

  hipLaunchKernelGGL(ode_kernel, dim3(GRID), dim3(THREADS), 0, stream,
                     y0, tt, W1, b1, W2, b2, out);
}